// Round 4
// baseline (1288.577 us; speedup 1.0000x reference)
//
#include <hip/hip_runtime.h>

// LSTMNet via MFMA: 2-layer LSTM (in=1, hid=32) + linear(32->1), B=2048, T=1024, fp32.
// Per step the recurrence is [B,32]@[32,128] per layer -> mfma_f32_16x16x32_bf16
// (K=32 in one instruction). fp32 accuracy kept via 3-term bf16 trunc-split:
//   A*B ~= Ahi*Bhi + Ahi*Blo + Alo*Bhi   (dropped AloBlo ~ 2^-16 rel)
// Block = 2 waves = one 16-row batch tile. Wave w owns hidden units 16w..16w+15
// = gate col-tiles {i,f,g,o}x16 -> i,f,g,o of a unit land on the SAME lane in
// C-layout (col=lane&15, row=4*(lane>>4)+reg) -> cell update is lane-local.
// h redistribution C-layout -> A-layout (lane&15=row, k=8*(lane>>4)+e) goes
// through a padded LDS buffer (stride 36 words keeps ds_read_b128 16B-aligned).
// Weights stay resident as B-fragments; MFMA reads AGPRs natively, so the
// 116-VGPR allocator cap seen in R1-R3 no longer forces per-use copies.

typedef float f32x4 __attribute__((ext_vector_type(4)));
typedef int   i32x4 __attribute__((ext_vector_type(4)));
typedef short s16x8 __attribute__((ext_vector_type(8)));

constexpr int TLEN = 1024;
constexpr int HID  = 32;
constexpr float L2E = 1.44269504088896f;

union FragU { i32x4 i; s16x8 s; };

static __device__ __forceinline__ float rcp_f(float v){ return __builtin_amdgcn_rcpf(v); }
static __device__ __forceinline__ float exp2_f(float v){ return __builtin_amdgcn_exp2f(v); }
static __device__ __forceinline__ float sigm_f(float x){
  return rcp_f(1.0f + exp2_f(x * (-L2E)));
}
static __device__ __forceinline__ float tanh_f(float x){
  return __builtin_fmaf(2.0f, rcp_f(1.0f + exp2_f(x * (-2.0f * L2E))), -1.0f);
}

static __device__ __forceinline__ f32x4 mfma16(s16x8 a, s16x8 b, f32x4 c){
  return __builtin_amdgcn_mfma_f32_16x16x32_bf16(a, b, c, 0, 0, 0);
}

// 8 consecutive fp32 (a[0..3],b[0..3], ascending k) -> bf16x8 hi + lo (trunc split).
// Exact: hi = trunc16(f); lo = f - hi (exact fp32 sub); lo truncated to bf16.
static __device__ __forceinline__ void split8(f32x4 a, f32x4 b, s16x8& hi, s16x8& lo){
  float f[8];
  #pragma unroll
  for (int e = 0; e < 4; ++e){ f[e] = a[e]; f[4 + e] = b[e]; }
  FragU H, L;
  #pragma unroll
  for (int p = 0; p < 4; ++p){
    unsigned u0 = __float_as_uint(f[2*p]);
    unsigned u1 = __float_as_uint(f[2*p + 1]);
    H.i[p] = (int)__builtin_amdgcn_perm(u1, u0, 0x07060302u);   // {hi16(f0), hi16(f1)}
    float l0 = f[2*p]     - __uint_as_float(u0 & 0xFFFF0000u);
    float l1 = f[2*p + 1] - __uint_as_float(u1 & 0xFFFF0000u);
    L.i[p] = (int)__builtin_amdgcn_perm(__float_as_uint(l1), __float_as_uint(l0), 0x07060302u);
  }
  hi = H.s; lo = L.s;
}

__global__ void __launch_bounds__(128, 1)
lstm2_mfma(const float* __restrict__ x,
           const float* __restrict__ Wih0, const float* __restrict__ Whh0,
           const float* __restrict__ bih0, const float* __restrict__ bhh0,
           const float* __restrict__ Wih1, const float* __restrict__ Whh1,
           const float* __restrict__ bih1, const float* __restrict__ bhh1,
           const float* __restrict__ Wlin, const float* __restrict__ blin,
           float* __restrict__ out)
{
  const int lane = threadIdx.x & 63;
  const int wid  = threadIdx.x >> 6;       // 0/1: unit-half of this wave
  const int m15  = lane & 15;
  const int m4   = lane >> 4;
  const int rowbase = blockIdx.x * 16;     // 16 batch rows per block
  const int u = 16 * wid + m15;            // hidden unit owned by this lane (C cols)

  __shared__ float h0buf[16 * 36];         // [row][unit], stride 36 (16B-aligned b128 reads)
  __shared__ float h1buf[16 * 36];
  __shared__ float xbuf[16 * 68];          // [row][t within chunk], stride 68

  // ---------------- one-time: weights -> B fragments, biases ----------------
  s16x8 B0h[4], B0l[4], BIh[4], BIl[4], BHh[4], BHl[4];
  float b0[4], wv0[4];
  f32x4 b1q[4];
  #pragma unroll
  for (int q = 0; q < 4; ++q){             // q: 0=i 1=f 2=g 3=o
    const int col = 32 * q + u;            // gate row in W == output column
    const int k0  = 8 * m4;
    {
      const float* p = Whh0 + col * HID + k0;
      split8(*(const f32x4*)p, *(const f32x4*)(p + 4), B0h[q], B0l[q]);
    }
    {
      const float* p = Wih1 + col * HID + k0;
      split8(*(const f32x4*)p, *(const f32x4*)(p + 4), BIh[q], BIl[q]);
    }
    {
      const float* p = Whh1 + col * HID + k0;
      split8(*(const f32x4*)p, *(const f32x4*)(p + 4), BHh[q], BHl[q]);
    }
    b0[q]  = bih0[col] + bhh0[col];
    wv0[q] = Wih0[col];
    const float bv = bih1[col] + bhh1[col];
    b1q[q] = (f32x4){bv, bv, bv, bv};
  }
  f32x4 wla = {0,0,0,0}, wlb = {0,0,0,0};
  float bl = 0.0f;
  if (wid == 0){
    wla = *(const f32x4*)(Wlin + 8 * m4);
    wlb = *(const f32x4*)(Wlin + 8 * m4 + 4);
    bl  = blin[0];
  }

  // ---------------- state ----------------
  s16x8 a0h, a0l, a1h, a1l;                // A-fragments of h0_prev / h1_prev
  { FragU z; z.i = (i32x4){0,0,0,0}; a0h = z.s; a0l = z.s; a1h = z.s; a1l = z.s; }
  float c0s[4] = {0,0,0,0}, c1s[4] = {0,0,0,0};

  for (int tc = 0; tc < TLEN / 64; ++tc){
    // stage this chunk's x: 16 rows x 64 t
    #pragma unroll
    for (int e = 0; e < 2; ++e){
      const int idx = (int)threadIdx.x * 2 + e;    // 0..255
      const int r = idx >> 4, c = idx & 15;
      *reinterpret_cast<f32x4*>(&xbuf[r * 68 + c * 4]) =
        *reinterpret_cast<const f32x4*>(&x[(size_t)(rowbase + r) * TLEN + tc * 64 + c * 4]);
    }
    __syncthreads();

    #pragma unroll 1
    for (int tt = 0; tt < 64; ++tt){
      // =============== layer 0 ===============
      float xr[4];
      #pragma unroll
      for (int i = 0; i < 4; ++i) xr[i] = xbuf[(4 * m4 + i) * 68 + tt];

      f32x4 G[4];
      #pragma unroll
      for (int q = 0; q < 4; ++q){
        #pragma unroll
        for (int i = 0; i < 4; ++i) G[q][i] = __builtin_fmaf(wv0[q], xr[i], b0[q]);
        G[q] = mfma16(a0h, B0h[q], G[q]);
        G[q] = mfma16(a0h, B0l[q], G[q]);
        G[q] = mfma16(a0l, B0h[q], G[q]);
      }
      float h0n[4];
      #pragma unroll
      for (int i = 0; i < 4; ++i){
        const float iv = sigm_f(G[0][i]);
        const float fv = sigm_f(G[1][i]);
        const float gv = tanh_f(G[2][i]);
        const float ov = sigm_f(G[3][i]);
        c0s[i] = __builtin_fmaf(fv, c0s[i], iv * gv);
        h0n[i] = ov * tanh_f(c0s[i]);
      }
      #pragma unroll
      for (int i = 0; i < 4; ++i) h0buf[(4 * m4 + i) * 36 + u] = h0n[i];
      __syncthreads();
      {
        const f32x4 fa = *(const f32x4*)&h0buf[m15 * 36 + 8 * m4];
        const f32x4 fb = *(const f32x4*)&h0buf[m15 * 36 + 8 * m4 + 4];
        split8(fa, fb, a0h, a0l);
      }

      // =============== layer 1 ===============
      f32x4 H[4];
      #pragma unroll
      for (int q = 0; q < 4; ++q){
        H[q] = mfma16(a0h, BIh[q], b1q[q]);
        H[q] = mfma16(a0h, BIl[q], H[q]);
        H[q] = mfma16(a0l, BIh[q], H[q]);
        H[q] = mfma16(a1h, BHh[q], H[q]);
        H[q] = mfma16(a1h, BHl[q], H[q]);
        H[q] = mfma16(a1l, BHh[q], H[q]);
      }
      float h1n[4];
      #pragma unroll
      for (int i = 0; i < 4; ++i){
        const float iv = sigm_f(H[0][i]);
        const float fv = sigm_f(H[1][i]);
        const float gv = tanh_f(H[2][i]);
        const float ov = sigm_f(H[3][i]);
        c1s[i] = __builtin_fmaf(fv, c1s[i], iv * gv);
        h1n[i] = ov * tanh_f(c1s[i]);
      }
      #pragma unroll
      for (int i = 0; i < 4; ++i) h1buf[(4 * m4 + i) * 36 + u] = h1n[i];
      __syncthreads();

      const f32x4 h1fa = *(const f32x4*)&h1buf[m15 * 36 + 8 * m4];
      const f32x4 h1fb = *(const f32x4*)&h1buf[m15 * 36 + 8 * m4 + 4];
      split8(h1fa, h1fb, a1h, a1l);

      // =============== linear head (wave 0 only) ===============
      if (wid == 0){
        float p = 0.0f;
        #pragma unroll
        for (int e = 0; e < 4; ++e){
          p = __builtin_fmaf(h1fa[e], wla[e], p);
          p = __builtin_fmaf(h1fb[e], wlb[e], p);
        }
        p += __shfl_xor(p, 16);
        p += __shfl_xor(p, 32);
        if (m4 == 0)
          out[(size_t)(rowbase + m15) * TLEN + (tc * 64 + tt)] = p + bl;
      }
    }
  }
}

extern "C" void kernel_launch(void* const* d_in, const int* in_sizes, int n_in,
                              void* d_out, int out_size, void* d_ws, size_t ws_size,
                              hipStream_t stream) {
  const float* x    = (const float*)d_in[0];
  const float* Wih0 = (const float*)d_in[1];
  const float* Whh0 = (const float*)d_in[2];
  const float* bih0 = (const float*)d_in[3];
  const float* bhh0 = (const float*)d_in[4];
  const float* Wih1 = (const float*)d_in[5];
  const float* Whh1 = (const float*)d_in[6];
  const float* bih1 = (const float*)d_in[7];
  const float* bhh1 = (const float*)d_in[8];
  const float* Wlin = (const float*)d_in[9];
  const float* blin = (const float*)d_in[10];
  float* outp = (float*)d_out;

  dim3 block(128);                 // 2 waves = one 16-row batch tile
  dim3 grid(2048 / 16);            // 128 blocks
  hipLaunchKernelGGL(lstm2_mfma, grid, block, 0, stream,
                     x, Wih0, Whh0, bih0, bhh0, Wih1, Whh1, bih1, bhh1,
                     Wlin, blin, outp);
}

// Round 5
// 943.107 us; speedup vs baseline: 1.3663x; 1.3663x over previous
//
#include <hip/hip_runtime.h>

// LSTMNet: 2-layer LSTM (in=1, hid=32) + linear(32->1), B=2048, T=1024, fp32.
// Scalar-VALU layout (R2) + v_dot2_f32_f16 packed dot products:
//  - one wave per batch row; 64 lanes = 32 hidden units x 2 halves
//    half 0, lane j: gate rows j (i) and 32+j (f)
//    half 1, lane j: gate rows 64+j (g) and 96+j (o)
//  - recurrent matvecs via fdot2 (2 MACs/instr, f16 inputs, f32 accum):
//    halves FMA count AND weight VGPRs (96 regs -> fits 128-reg tier, no
//    spills -- R1-R3's 1.7x instruction inflation came from spill copies)
//  - h broadcast as PACKED f16 pairs: 32 readlanes/step (vs 96), results are
//    wave-uniform -> live in SGPRs, reused by both L0-next and L1 consumers.

typedef _Float16 h2 __attribute__((ext_vector_type(2)));

constexpr int BATCH = 2048;
constexpr int TLEN  = 1024;
constexpr int HID   = 32;
constexpr float L2E = 1.44269504088896f;   // log2(e)

static __device__ __forceinline__ float rcp_f(float v){ return __builtin_amdgcn_rcpf(v); }
static __device__ __forceinline__ float exp2_f(float v){ return __builtin_amdgcn_exp2f(v); }
static __device__ __forceinline__ float bcast(float v, int k){
    return __int_as_float(__builtin_amdgcn_readlane(__float_as_int(v), k));
}
static __device__ __forceinline__ float dot2(h2 a, h2 b, float c){
#if __has_builtin(__builtin_amdgcn_fdot2)
    return __builtin_amdgcn_fdot2(a, b, c, false);
#else
    return c + (float)a.x * (float)b.x + (float)a.y * (float)b.y;
#endif
}
static __device__ __forceinline__ h2 pk(float a, float b){
    h2 r; r.x = (_Float16)a; r.y = (_Float16)b; return r;   // RNE converts
}
static __device__ __forceinline__ h2 asp(int v){ return __builtin_bit_cast(h2, v); }

__global__ void __launch_bounds__(256)
lstm2_dot2(const float* __restrict__ x,
           const float* __restrict__ Wih0, const float* __restrict__ Whh0,
           const float* __restrict__ bih0, const float* __restrict__ bhh0,
           const float* __restrict__ Wih1, const float* __restrict__ Whh1,
           const float* __restrict__ bih1, const float* __restrict__ bhh1,
           const float* __restrict__ Wlin, const float* __restrict__ blin,
           float* __restrict__ out)
{
    const int lane = threadIdx.x & 63;
    const int b    = blockIdx.x * (blockDim.x >> 6) + (threadIdx.x >> 6);
    const int j    = lane & 31;
    const int hi   = lane >> 5;          // 0: i,f rows   1: g,o rows

    const int rowA = hi * 64 + j;        // i (hi=0) / g (hi=1)
    const int rowB = rowA + 32;          // f (hi=0) / o (hi=1)

    // ---- per-lane weights, packed to f16 pairs (RNE) ----
    const float wih0_a = Wih0[rowA];
    const float wih0_b = Wih0[rowB];
    const float ba0 = bih0[rowA] + bhh0[rowA];
    const float bb0 = bih0[rowB] + bhh0[rowB];
    const float ba1 = bih1[rowA] + bhh1[rowA];
    const float bb1 = bih1[rowB] + bhh1[rowB];

    h2 wA0[16], wB0[16], iA1[16], iB1[16], hA1[16], hB1[16];
    #pragma unroll
    for (int m = 0; m < 16; ++m){
        wA0[m] = pk(Whh0[rowA * HID + 2*m], Whh0[rowA * HID + 2*m + 1]);
        wB0[m] = pk(Whh0[rowB * HID + 2*m], Whh0[rowB * HID + 2*m + 1]);
        iA1[m] = pk(Wih1[rowA * HID + 2*m], Wih1[rowA * HID + 2*m + 1]);
        iB1[m] = pk(Wih1[rowB * HID + 2*m], Wih1[rowB * HID + 2*m + 1]);
        hA1[m] = pk(Whh1[rowA * HID + 2*m], Whh1[rowA * HID + 2*m + 1]);
        hB1[m] = pk(Whh1[rowB * HID + 2*m], Whh1[rowB * HID + 2*m + 1]);
    }
    const float wl = Wlin[j];            // same on both halves (h1 replicated)
    const float bl = blin[0];

    // activation-"a" selector: half0 -> sigmoid, half1 -> tanh (=2*sigm(2x)-1)
    const float kA = hi ? (-2.0f * L2E) : (-L2E);
    const float mA = hi ?  2.0f : 1.0f;
    const float cA = hi ? -1.0f : 0.0f;

    float h0 = 0.0f, c0 = 0.0f, h1 = 0.0f, c1 = 0.0f;
    int h0s[16], h1s[16];                // packed h pairs, wave-uniform (SGPRs)
    #pragma unroll
    for (int m = 0; m < 16; ++m){ h0s[m] = 0; h1s[m] = 0; }

    const float* xrow = x   + (size_t)b * TLEN;
    float*       orow = out + (size_t)b * TLEN;

    for (int tc = 0; tc < TLEN / 64; ++tc){
        const float xchunk = xrow[tc * 64 + lane];   // coalesced, 64 steps' worth
        float ychunk = 0.0f;

        for (int tt = 0; tt < 64; ++tt){
            const float xt = bcast(xchunk, tt);

            // ================= layer 0 =================
            float ga  = __builtin_fmaf(wih0_a, xt, ba0);
            float gb  = __builtin_fmaf(wih0_b, xt, bb0);
            float ga2 = 0.0f, gb2 = 0.0f;
            #pragma unroll
            for (int m = 0; m < 16; m += 2){
                ga  = dot2(wA0[m],     asp(h0s[m]),     ga);
                gb  = dot2(wB0[m],     asp(h0s[m]),     gb);
                ga2 = dot2(wA0[m + 1], asp(h0s[m + 1]), ga2);
                gb2 = dot2(wB0[m + 1], asp(h0s[m + 1]), gb2);
            }
            ga += ga2; gb += gb2;

            float act_a = __builtin_fmaf(mA, rcp_f(1.0f + exp2_f(ga * kA)), cA);
            float act_b = rcp_f(1.0f + exp2_f(gb * (-L2E)));
            const float oa = __shfl_xor(act_a, 32);
            const float ob = __shfl_xor(act_b, 32);
            {
                const float fsel = hi ? ob : act_b;
                const float osel = hi ? act_b : ob;
                c0 = __builtin_fmaf(fsel, c0, act_a * oa);
                const float t0 = __builtin_fmaf(2.0f,
                        rcp_f(1.0f + exp2_f(c0 * (-2.0f * L2E))), -1.0f);
                h0 = osel * t0;
            }
            // pack h0 pairs (RNE) and hoist to SGPRs
            {
                const float o0 = __shfl_xor(h0, 1);
                const h2 p0 = pk((lane & 1) ? o0 : h0, (lane & 1) ? h0 : o0);
                const int p0i = __builtin_bit_cast(int, p0);
                #pragma unroll
                for (int m = 0; m < 16; ++m)
                    h0s[m] = __builtin_amdgcn_readlane(p0i, 2 * m);
            }

            // ================= layer 1 =================
            float p_a = ba1, p_b = bb1, p_a2 = 0.0f, p_b2 = 0.0f;
            float q_a = 0.0f, q_b = 0.0f, q_a2 = 0.0f, q_b2 = 0.0f;
            #pragma unroll
            for (int m = 0; m < 16; m += 2){
                p_a  = dot2(iA1[m],     asp(h0s[m]),     p_a);
                p_b  = dot2(iB1[m],     asp(h0s[m]),     p_b);
                p_a2 = dot2(iA1[m + 1], asp(h0s[m + 1]), p_a2);
                p_b2 = dot2(iB1[m + 1], asp(h0s[m + 1]), p_b2);
                q_a  = dot2(hA1[m],     asp(h1s[m]),     q_a);
                q_b  = dot2(hB1[m],     asp(h1s[m]),     q_b);
                q_a2 = dot2(hA1[m + 1], asp(h1s[m + 1]), q_a2);
                q_b2 = dot2(hB1[m + 1], asp(h1s[m + 1]), q_b2);
            }
            const float ga1 = (p_a + p_a2) + (q_a + q_a2);
            const float gb1 = (p_b + p_b2) + (q_b + q_b2);

            float act_a1 = __builtin_fmaf(mA, rcp_f(1.0f + exp2_f(ga1 * kA)), cA);
            float act_b1 = rcp_f(1.0f + exp2_f(gb1 * (-L2E)));
            const float oa1 = __shfl_xor(act_a1, 32);
            const float ob1 = __shfl_xor(act_b1, 32);
            {
                const float fsel = hi ? ob1 : act_b1;
                const float osel = hi ? act_b1 : ob1;
                c1 = __builtin_fmaf(fsel, c1, act_a1 * oa1);
                const float t1 = __builtin_fmaf(2.0f,
                        rcp_f(1.0f + exp2_f(c1 * (-2.0f * L2E))), -1.0f);
                h1 = osel * t1;
            }
            // pack h1 pairs
            {
                const float o1 = __shfl_xor(h1, 1);
                const h2 p1 = pk((lane & 1) ? o1 : h1, (lane & 1) ? h1 : o1);
                const int p1i = __builtin_bit_cast(int, p1);
                #pragma unroll
                for (int m = 0; m < 16; ++m)
                    h1s[m] = __builtin_amdgcn_readlane(p1i, 2 * m);
            }

            // ================= linear head =================
            // h1 replicated across halves -> 32-lane reduce gives full dot.
            float p = wl * h1;
            #pragma unroll
            for (int m = 16; m >= 1; m >>= 1) p += __shfl_xor(p, m);
            const float y = p + bl;
            ychunk = (lane == tt) ? y : ychunk;
        }

        orow[tc * 64 + lane] = ychunk;   // coalesced store, 64 outputs
    }
}

extern "C" void kernel_launch(void* const* d_in, const int* in_sizes, int n_in,
                              void* d_out, int out_size, void* d_ws, size_t ws_size,
                              hipStream_t stream) {
    const float* x    = (const float*)d_in[0];
    const float* Wih0 = (const float*)d_in[1];
    const float* Whh0 = (const float*)d_in[2];
    const float* bih0 = (const float*)d_in[3];
    const float* bhh0 = (const float*)d_in[4];
    const float* Wih1 = (const float*)d_in[5];
    const float* Whh1 = (const float*)d_in[6];
    const float* bih1 = (const float*)d_in[7];
    const float* bhh1 = (const float*)d_in[8];
    const float* Wlin = (const float*)d_in[9];
    const float* blin = (const float*)d_in[10];
    float* outp = (float*)d_out;

    dim3 block(256);
    dim3 grid(BATCH / (256 / 64));   // 4 waves/block, 1 batch element per wave
    hipLaunchKernelGGL(lstm2_dot2, grid, block, 0, stream,
                       x, Wih0, Whh0, bih0, bhh0, Wih1, Whh1, bih1, bhh1,
                       Wlin, blin, outp);
}

// Round 6
// 801.288 us; speedup vs baseline: 1.6081x; 1.1770x over previous
//
#include <hip/hip_runtime.h>

// LSTMNet: 2-layer LSTM (in=1, hid=32) + linear(32->1), B=2048, T=1024, fp32.
// R6: scalar dot2 layout (R5) with the broadcast machinery moved to LDS.
//  - one wave per batch row; 64 lanes = 32 hidden units x 2 halves
//    half 0, lane j: gate rows j (i) and 32+j (f)
//    half 1, lane j: gate rows 64+j (g) and 96+j (o)
//  - recurrent matvecs via v_dot2_f32_f16 (f16 inputs, f32 accum), weights
//    resident in VGPRs (96 h2 regs).
//  - h "broadcast": lane writes its unit's h as ONE f16 (ds_write_b16), all
//    lanes read packed pairs back with wave-uniform ds_read_b128 (broadcast,
//    conflict-free). Replaces 32 v_readlane + pack sequences per step.
//  - cross-half i,f<->g,o exchange: single ds_bpermute with a PREcomputed
//    (lane^32)*4 address (1 instr vs ~3 for __shfl_xor).
//  - head: y = Wlin.h1 computed REDUNDANTLY per lane via 16 dot2 against an
//    LDS f16 Wlin copy (kills the 6-deep dependent swizzle reduce chain).
//  - no __syncthreads anywhere: each wave owns its LDS slice.

typedef _Float16 h2 __attribute__((ext_vector_type(2)));
typedef _Float16 h8 __attribute__((ext_vector_type(8)));

constexpr int BATCH = 2048;
constexpr int TLEN  = 1024;
constexpr int HID   = 32;
constexpr float L2E = 1.44269504088896f;   // log2(e)

union H8U { h8 v; h2 p[4]; };

static __device__ __forceinline__ float rcp_f(float v){ return __builtin_amdgcn_rcpf(v); }
static __device__ __forceinline__ float exp2_f(float v){ return __builtin_amdgcn_exp2f(v); }
static __device__ __forceinline__ float bcastf(float v, int k){
    return __int_as_float(__builtin_amdgcn_readlane(__float_as_int(v), k));
}
static __device__ __forceinline__ float dot2(h2 a, h2 b, float c){
#if __has_builtin(__builtin_amdgcn_fdot2)
    return __builtin_amdgcn_fdot2(a, b, c, false);
#else
    return c + (float)a.x * (float)b.x + (float)a.y * (float)b.y;
#endif
}
static __device__ __forceinline__ h2 pkh(float a, float b){
    h2 r; r.x = (_Float16)a; r.y = (_Float16)b; return r;   // RNE
}
static __device__ __forceinline__ float xchg32(float v, int xaddr){
    return __int_as_float(__builtin_amdgcn_ds_bpermute(xaddr, __float_as_int(v)));
}

__global__ void __launch_bounds__(256)
lstm2_v6(const float* __restrict__ x,
         const float* __restrict__ Wih0, const float* __restrict__ Whh0,
         const float* __restrict__ bih0, const float* __restrict__ bhh0,
         const float* __restrict__ Wih1, const float* __restrict__ Whh1,
         const float* __restrict__ bih1, const float* __restrict__ bhh1,
         const float* __restrict__ Wlin, const float* __restrict__ blin,
         float* __restrict__ out)
{
    const int tid  = threadIdx.x;
    const int lane = tid & 63;
    const int w    = tid >> 6;                 // wave within block (4/block)
    const int b    = blockIdx.x * 4 + w;       // batch row
    const int j    = lane & 31;
    const int hi   = lane >> 5;                // 0: i,f rows   1: g,o rows
    const int rowA = hi * 64 + j;              // i (hi=0) / g (hi=1)
    const int rowB = rowA + 32;                // f (hi=0) / o (hi=1)
    const int xaddr = (lane ^ 32) << 2;        // bpermute byte addr, precomputed

    __shared__ h8 hb0[4][4];                   // per-wave h0 (32 f16)
    __shared__ h8 hb1[4][4];                   // per-wave h1 (32 f16)
    __shared__ h8 wlb[4][4];                   // per-wave f16 copy of Wlin
    _Float16* h0p = (_Float16*)&hb0[w][0];
    _Float16* h1p = (_Float16*)&hb1[w][0];

    // wave-local LDS init (both halves write identical values; no barriers)
    h0p[j] = (_Float16)0.0f;
    h1p[j] = (_Float16)0.0f;
    ((_Float16*)&wlb[w][0])[j] = (_Float16)Wlin[j];

    // ---- per-lane weights, packed f16 pairs (96 VGPRs) ----
    h2 wA0[16], wB0[16], iA1[16], iB1[16], hA1[16], hB1[16];
    #pragma unroll
    for (int m = 0; m < 16; ++m){
        wA0[m] = pkh(Whh0[rowA * HID + 2*m], Whh0[rowA * HID + 2*m + 1]);
        wB0[m] = pkh(Whh0[rowB * HID + 2*m], Whh0[rowB * HID + 2*m + 1]);
        iA1[m] = pkh(Wih1[rowA * HID + 2*m], Wih1[rowA * HID + 2*m + 1]);
        iB1[m] = pkh(Wih1[rowB * HID + 2*m], Wih1[rowB * HID + 2*m + 1]);
        hA1[m] = pkh(Whh1[rowA * HID + 2*m], Whh1[rowA * HID + 2*m + 1]);
        hB1[m] = pkh(Whh1[rowB * HID + 2*m], Whh1[rowB * HID + 2*m + 1]);
    }
    const float wa0 = Wih0[rowA];
    const float wb0 = Wih0[rowB];
    const float ba0 = bih0[rowA] + bhh0[rowA];
    const float bb0 = bih0[rowB] + bhh0[rowB];
    const float ba1 = bih1[rowA] + bhh1[rowA];
    const float bb1 = bih1[rowB] + bhh1[rowB];
    const float bl  = blin[0];

    // act-"a" selector: half0 -> sigmoid, half1 -> tanh (=2*sigm(2x)-1)
    const float kA = hi ? (-2.0f * L2E) : (-L2E);
    const float mA = hi ?  2.0f : 1.0f;
    const float cA = hi ? -1.0f : 0.0f;

    float c0 = 0.0f, c1 = 0.0f;

    const float* xrow = x   + (size_t)b * TLEN;
    float*       orow = out + (size_t)b * TLEN;

    for (int tc = 0; tc < TLEN / 64; ++tc){
        const float xchunk = xrow[tc * 64 + lane];   // coalesced, 64 steps' worth
        float ychunk = 0.0f;

        for (int tt = 0; tt < 64; ++tt){
            const float xt = bcastf(xchunk, tt);

            // ================= layer 0: g = Whh0*h0_prev + Wih0*x + b =========
            float ga  = __builtin_fmaf(wa0, xt, ba0);
            float gb  = __builtin_fmaf(wb0, xt, bb0);
            float ga2 = 0.0f, gb2 = 0.0f;
            #pragma unroll
            for (int m = 0; m < 4; ++m){
                H8U hh; hh.v = hb0[w][m];            // broadcast read (h0_prev)
                ga  = dot2(wA0[4*m+0], hh.p[0], ga );
                gb  = dot2(wB0[4*m+0], hh.p[0], gb );
                ga2 = dot2(wA0[4*m+1], hh.p[1], ga2);
                gb2 = dot2(wB0[4*m+1], hh.p[1], gb2);
                ga  = dot2(wA0[4*m+2], hh.p[2], ga );
                gb  = dot2(wB0[4*m+2], hh.p[2], gb );
                ga2 = dot2(wA0[4*m+3], hh.p[3], ga2);
                gb2 = dot2(wB0[4*m+3], hh.p[3], gb2);
            }
            ga += ga2; gb += gb2;

            float act_a = __builtin_fmaf(mA, rcp_f(1.0f + exp2_f(ga * kA)), cA);
            float act_b = rcp_f(1.0f + exp2_f(gb * (-L2E)));
            const float oa = xchg32(act_a, xaddr);
            const float ob = xchg32(act_b, xaddr);
            {
                const float fsel = hi ? ob : act_b;
                const float osel = hi ? act_b : ob;
                c0 = __builtin_fmaf(fsel, c0, act_a * oa);
                const float t0 = __builtin_fmaf(2.0f,
                        rcp_f(1.0f + exp2_f(c0 * (-2.0f * L2E))), -1.0f);
                const float h0 = osel * t0;
                h0p[j] = (_Float16)h0;               // ds_write_b16 (both halves same)
            }

            // ================= layer 1: g = Wih1*h0_new + Whh1*h1_prev + b ====
            float pa = ba1, pb = bb1, qa = 0.0f, qb = 0.0f;
            #pragma unroll
            for (int m = 0; m < 4; ++m){
                H8U hn; hn.v = hb0[w][m];            // h0_NEW (after write)
                H8U ho; ho.v = hb1[w][m];            // h1_prev
                pa = dot2(iA1[4*m+0], hn.p[0], pa);
                pb = dot2(iB1[4*m+0], hn.p[0], pb);
                qa = dot2(hA1[4*m+0], ho.p[0], qa);
                qb = dot2(hB1[4*m+0], ho.p[0], qb);
                pa = dot2(iA1[4*m+1], hn.p[1], pa);
                pb = dot2(iB1[4*m+1], hn.p[1], pb);
                qa = dot2(hA1[4*m+1], ho.p[1], qa);
                qb = dot2(hB1[4*m+1], ho.p[1], qb);
                pa = dot2(iA1[4*m+2], hn.p[2], pa);
                pb = dot2(iB1[4*m+2], hn.p[2], pb);
                qa = dot2(hA1[4*m+2], ho.p[2], qa);
                qb = dot2(hB1[4*m+2], ho.p[2], qb);
                pa = dot2(iA1[4*m+3], hn.p[3], pa);
                pb = dot2(iB1[4*m+3], hn.p[3], pb);
                qa = dot2(hA1[4*m+3], ho.p[3], qa);
                qb = dot2(hB1[4*m+3], ho.p[3], qb);
            }
            const float g1a = pa + qa;
            const float g1b = pb + qb;

            float act_a1 = __builtin_fmaf(mA, rcp_f(1.0f + exp2_f(g1a * kA)), cA);
            float act_b1 = rcp_f(1.0f + exp2_f(g1b * (-L2E)));
            const float oa1 = xchg32(act_a1, xaddr);
            const float ob1 = xchg32(act_b1, xaddr);
            {
                const float fsel = hi ? ob1 : act_b1;
                const float osel = hi ? act_b1 : ob1;
                c1 = __builtin_fmaf(fsel, c1, act_a1 * oa1);
                const float t1 = __builtin_fmaf(2.0f,
                        rcp_f(1.0f + exp2_f(c1 * (-2.0f * L2E))), -1.0f);
                const float h1 = osel * t1;
                h1p[j] = (_Float16)h1;               // ds_write_b16
            }

            // ================= linear head: redundant per-lane dot ===========
            float y = bl, y2 = 0.0f;
            #pragma unroll
            for (int m = 0; m < 4; ++m){
                H8U hw; hw.v = wlb[w][m];            // broadcast Wlin chunk
                H8U hn; hn.v = hb1[w][m];            // h1_NEW (after write)
                y  = dot2(hw.p[0], hn.p[0], y );
                y2 = dot2(hw.p[1], hn.p[1], y2);
                y  = dot2(hw.p[2], hn.p[2], y );
                y2 = dot2(hw.p[3], hn.p[3], y2);
            }
            y += y2;
            ychunk = (lane == tt) ? y : ychunk;
        }

        orow[tc * 64 + lane] = ychunk;               // coalesced store
    }
}

extern "C" void kernel_launch(void* const* d_in, const int* in_sizes, int n_in,
                              void* d_out, int out_size, void* d_ws, size_t ws_size,
                              hipStream_t stream) {
    const float* x    = (const float*)d_in[0];
    const float* Wih0 = (const float*)d_in[1];
    const float* Whh0 = (const float*)d_in[2];
    const float* bih0 = (const float*)d_in[3];
    const float* bhh0 = (const float*)d_in[4];
    const float* Wih1 = (const float*)d_in[5];
    const float* Whh1 = (const float*)d_in[6];
    const float* bih1 = (const float*)d_in[7];
    const float* bhh1 = (const float*)d_in[8];
    const float* Wlin = (const float*)d_in[9];
    const float* blin = (const float*)d_in[10];
    float* outp = (float*)d_out;

    dim3 block(256);
    dim3 grid(BATCH / 4);            // 4 waves/block, 1 batch row per wave
    hipLaunchKernelGGL(lstm2_v6, grid, block, 0, stream,
                       x, Wih0, Whh0, bih0, bhh0, Wih1, Whh1, bih1, bhh1,
                       Wlin, blin, outp);
}

// Round 7
// 709.642 us; speedup vs baseline: 1.8158x; 1.1291x over previous
//
#include <hip/hip_runtime.h>

// LSTMNet: 2-layer LSTM (in=1, hid=32) + linear(32->1), B=2048, T=1024, fp32.
// R7 = R6 structure + three changes:
//  (1) asm-volatile PIN on all 96 packed weight regs + bias scalars. R1-R6's
//      2x instruction inflation was the RA REMATERIALIZING invariant global
//      weight loads inside the 64K-iter loop (VGPR_Count 88 < the 96 weights
//      that must be live proves it). A "+v" asm def is not rematable.
//  (2) h0/h1 broadcast pairs kept in VGPRs across steps: write b16 + 4
//      wave-uniform b128 reads per layer per step (8 DS reads vs 16).
//  (3) head hoisted out of the step loop: h1 is stored per-step in
//      hstore[tt]; at chunk end lane t computes y[t] = Wlin.hstore[t] once.
//      Kills 17 VALU + 8 DS per step.
// One wave per batch row; 64 lanes = 32 units x 2 halves (i,f | g,o).

typedef _Float16 h2 __attribute__((ext_vector_type(2)));
typedef _Float16 h8 __attribute__((ext_vector_type(8)));

constexpr int BATCH = 2048;
constexpr int TLEN  = 1024;
constexpr int HID   = 32;
constexpr float L2E = 1.44269504088896f;   // log2(e)

union H8U { h8 v; h2 p[4]; };

static __device__ __forceinline__ float rcp_f(float v){ return __builtin_amdgcn_rcpf(v); }
static __device__ __forceinline__ float exp2_f(float v){ return __builtin_amdgcn_exp2f(v); }
static __device__ __forceinline__ float bcastf(float v, int k){
    return __int_as_float(__builtin_amdgcn_readlane(__float_as_int(v), k));
}
static __device__ __forceinline__ float dot2(h2 a, h2 b, float c){
#if __has_builtin(__builtin_amdgcn_fdot2)
    return __builtin_amdgcn_fdot2(a, b, c, false);
#else
    return c + (float)a.x * (float)b.x + (float)a.y * (float)b.y;
#endif
}
static __device__ __forceinline__ int pki(float a, float b){
    h2 r; r.x = (_Float16)a; r.y = (_Float16)b;      // RNE converts
    return __builtin_bit_cast(int, r);
}
static __device__ __forceinline__ h2 asp(int v){ return __builtin_bit_cast(h2, v); }
static __device__ __forceinline__ float xchg32(float v, int xaddr){
    return __int_as_float(__builtin_amdgcn_ds_bpermute(xaddr, __float_as_int(v)));
}

__global__ void __launch_bounds__(256) __attribute__((amdgpu_waves_per_eu(2, 2)))
lstm2_v7(const float* __restrict__ x,
         const float* __restrict__ Wih0, const float* __restrict__ Whh0,
         const float* __restrict__ bih0, const float* __restrict__ bhh0,
         const float* __restrict__ Wih1, const float* __restrict__ Whh1,
         const float* __restrict__ bih1, const float* __restrict__ bhh1,
         const float* __restrict__ Wlin, const float* __restrict__ blin,
         float* __restrict__ out)
{
    const int tid  = threadIdx.x;
    const int lane = tid & 63;
    const int w    = tid >> 6;                 // wave within block
    const int b    = blockIdx.x * 4 + w;       // batch row
    const int j    = lane & 31;
    const int hi   = lane >> 5;                // 0: i,f rows   1: g,o rows
    const int rowA = hi * 64 + j;              // i (hi=0) / g (hi=1)
    const int rowB = rowA + 32;                // f (hi=0) / o (hi=1)
    const int xaddr = (lane ^ 32) << 2;        // bpermute byte addr

    __shared__ alignas(16) _Float16 hb0s[4][32];        // h0 transpose buffer
    __shared__ alignas(16) _Float16 hstore[4][64][40];  // h1 per step, 80B stride
    __shared__ alignas(16) _Float16 wls[4][32];         // f16 Wlin copy

    _Float16* hb0p = &hb0s[w][0];

    // wave-local LDS init (both halves write identical values; no barriers)
    wls[w][j] = (_Float16)Wlin[j];

    // ---- per-lane weights, packed f16 pairs, PINNED in VGPRs ----
    int wA0i[16], wB0i[16], iA1i[16], iB1i[16], hA1i[16], hB1i[16];
    #pragma unroll
    for (int m = 0; m < 16; ++m){
        wA0i[m] = pki(Whh0[rowA * HID + 2*m], Whh0[rowA * HID + 2*m + 1]);
        wB0i[m] = pki(Whh0[rowB * HID + 2*m], Whh0[rowB * HID + 2*m + 1]);
        iA1i[m] = pki(Wih1[rowA * HID + 2*m], Wih1[rowA * HID + 2*m + 1]);
        iB1i[m] = pki(Wih1[rowB * HID + 2*m], Wih1[rowB * HID + 2*m + 1]);
        hA1i[m] = pki(Whh1[rowA * HID + 2*m], Whh1[rowA * HID + 2*m + 1]);
        hB1i[m] = pki(Whh1[rowB * HID + 2*m], Whh1[rowB * HID + 2*m + 1]);
    }
    #pragma unroll
    for (int m = 0; m < 16; ++m){
        asm volatile("" : "+v"(wA0i[m]), "+v"(wB0i[m]), "+v"(iA1i[m]),
                          "+v"(iB1i[m]), "+v"(hA1i[m]), "+v"(hB1i[m]));
    }

    float wa0 = Wih0[rowA];
    float wb0 = Wih0[rowB];
    float ba0 = bih0[rowA] + bhh0[rowA];
    float bb0 = bih0[rowB] + bhh0[rowB];
    float ba1 = bih1[rowA] + bhh1[rowA];
    float bb1 = bih1[rowB] + bhh1[rowB];
    float bl  = blin[0];
    asm volatile("" : "+v"(wa0), "+v"(wb0), "+v"(ba0), "+v"(bb0),
                      "+v"(ba1), "+v"(bb1), "+v"(bl));

    // act-"a" selector: half0 -> sigmoid, half1 -> tanh (=2*sigm(2x)-1)
    const float kA = hi ? (-2.0f * L2E) : (-L2E);
    const float mA = hi ?  2.0f : 1.0f;
    const float cA = hi ? -1.0f : 0.0f;

    float c0 = 0.0f, c1 = 0.0f;
    H8U hp0[4], hp1[4];                        // h0/h1 as packed pairs (regs)
    #pragma unroll
    for (int m = 0; m < 4; ++m){
        hp0[m].v = (h8)(_Float16)0.0f;
        hp1[m].v = (h8)(_Float16)0.0f;
    }

    const float* xrow = x   + (size_t)b * TLEN;
    float*       orow = out + (size_t)b * TLEN;

    for (int tc = 0; tc < TLEN / 64; ++tc){
        const float xchunk = xrow[tc * 64 + lane];   // coalesced, 64 steps

        for (int tt = 0; tt < 64; ++tt){
            const float xt = bcastf(xchunk, tt);

            // ========= layer 0: g = Whh0*h0_prev + Wih0*x + b =========
            float ga  = __builtin_fmaf(wa0, xt, ba0);
            float gb  = __builtin_fmaf(wb0, xt, bb0);
            float ga2 = 0.0f, gb2 = 0.0f;
            #pragma unroll
            for (int m = 0; m < 4; ++m){
                ga  = dot2(asp(wA0i[4*m+0]), hp0[m].p[0], ga );
                gb  = dot2(asp(wB0i[4*m+0]), hp0[m].p[0], gb );
                ga2 = dot2(asp(wA0i[4*m+1]), hp0[m].p[1], ga2);
                gb2 = dot2(asp(wB0i[4*m+1]), hp0[m].p[1], gb2);
                ga  = dot2(asp(wA0i[4*m+2]), hp0[m].p[2], ga );
                gb  = dot2(asp(wB0i[4*m+2]), hp0[m].p[2], gb );
                ga2 = dot2(asp(wA0i[4*m+3]), hp0[m].p[3], ga2);
                gb2 = dot2(asp(wB0i[4*m+3]), hp0[m].p[3], gb2);
            }
            ga += ga2; gb += gb2;

            float act_a = __builtin_fmaf(mA, rcp_f(1.0f + exp2_f(ga * kA)), cA);
            float act_b = rcp_f(1.0f + exp2_f(gb * (-L2E)));
            const float oa = xchg32(act_a, xaddr);
            const float ob = xchg32(act_b, xaddr);
            {
                const float fsel = hi ? ob : act_b;
                const float osel = hi ? act_b : ob;
                c0 = __builtin_fmaf(fsel, c0, act_a * oa);
                const float t0 = __builtin_fmaf(2.0f,
                        rcp_f(1.0f + exp2_f(c0 * (-2.0f * L2E))), -1.0f);
                const float h0 = osel * t0;
                hb0p[j] = (_Float16)h0;              // ds_write_b16 (both halves same)
            }
            // read h0_new back as packed pairs (wave-uniform broadcast b128)
            {
                const h8* hv = (const h8*)hb0p;
                #pragma unroll
                for (int m = 0; m < 4; ++m) hp0[m].v = hv[m];
            }

            // ========= layer 1: g = Wih1*h0_new + Whh1*h1_prev + b =========
            float pa = ba1, pb = bb1, pa2 = 0.0f, pb2 = 0.0f;
            float qa = 0.0f, qb = 0.0f, qa2 = 0.0f, qb2 = 0.0f;
            #pragma unroll
            for (int m = 0; m < 4; ++m){
                pa  = dot2(asp(iA1i[4*m+0]), hp0[m].p[0], pa );
                pb  = dot2(asp(iB1i[4*m+0]), hp0[m].p[0], pb );
                qa  = dot2(asp(hA1i[4*m+0]), hp1[m].p[0], qa );
                qb  = dot2(asp(hB1i[4*m+0]), hp1[m].p[0], qb );
                pa2 = dot2(asp(iA1i[4*m+1]), hp0[m].p[1], pa2);
                pb2 = dot2(asp(iB1i[4*m+1]), hp0[m].p[1], pb2);
                qa2 = dot2(asp(hA1i[4*m+1]), hp1[m].p[1], qa2);
                qb2 = dot2(asp(hB1i[4*m+1]), hp1[m].p[1], qb2);
                pa  = dot2(asp(iA1i[4*m+2]), hp0[m].p[2], pa );
                pb  = dot2(asp(iB1i[4*m+2]), hp0[m].p[2], pb );
                qa  = dot2(asp(hA1i[4*m+2]), hp1[m].p[2], qa );
                qb  = dot2(asp(hB1i[4*m+2]), hp1[m].p[2], qb );
                pa2 = dot2(asp(iA1i[4*m+3]), hp0[m].p[3], pa2);
                pb2 = dot2(asp(iB1i[4*m+3]), hp0[m].p[3], pb2);
                qa2 = dot2(asp(hA1i[4*m+3]), hp1[m].p[3], qa2);
                qb2 = dot2(asp(hB1i[4*m+3]), hp1[m].p[3], qb2);
            }
            const float g1a = (pa + pa2) + (qa + qa2);
            const float g1b = (pb + pb2) + (qb + qb2);

            float act_a1 = __builtin_fmaf(mA, rcp_f(1.0f + exp2_f(g1a * kA)), cA);
            float act_b1 = rcp_f(1.0f + exp2_f(g1b * (-L2E)));
            const float oa1 = xchg32(act_a1, xaddr);
            const float ob1 = xchg32(act_b1, xaddr);
            {
                const float fsel = hi ? ob1 : act_b1;
                const float osel = hi ? act_b1 : ob1;
                c1 = __builtin_fmaf(fsel, c1, act_a1 * oa1);
                const float t1 = __builtin_fmaf(2.0f,
                        rcp_f(1.0f + exp2_f(c1 * (-2.0f * L2E))), -1.0f);
                const float h1 = osel * t1;
                hstore[w][tt][j] = (_Float16)h1;     // ds_write_b16 per-step slot
            }
            // read h1_new back (wave-uniform) for next step's recurrence
            {
                const h8* hv = (const h8*)&hstore[w][tt][0];
                #pragma unroll
                for (int m = 0; m < 4; ++m) hp1[m].v = hv[m];
            }
        }

        // ========= head for the whole chunk: lane t -> y[t] =========
        {
            H8U wl4[4], hr[4];
            const h8* wv = (const h8*)&wls[w][0];
            const h8* hv = (const h8*)&hstore[w][lane][0];
            #pragma unroll
            for (int m = 0; m < 4; ++m){ wl4[m].v = wv[m]; hr[m].v = hv[m]; }
            float y = bl, y2 = 0.0f;
            #pragma unroll
            for (int m = 0; m < 4; ++m){
                y  = dot2(wl4[m].p[0], hr[m].p[0], y );
                y2 = dot2(wl4[m].p[1], hr[m].p[1], y2);
                y  = dot2(wl4[m].p[2], hr[m].p[2], y );
                y2 = dot2(wl4[m].p[3], hr[m].p[3], y2);
            }
            orow[tc * 64 + lane] = y + y2;           // coalesced store
        }
    }
}

extern "C" void kernel_launch(void* const* d_in, const int* in_sizes, int n_in,
                              void* d_out, int out_size, void* d_ws, size_t ws_size,
                              hipStream_t stream) {
    const float* x    = (const float*)d_in[0];
    const float* Wih0 = (const float*)d_in[1];
    const float* Whh0 = (const float*)d_in[2];
    const float* bih0 = (const float*)d_in[3];
    const float* bhh0 = (const float*)d_in[4];
    const float* Wih1 = (const float*)d_in[5];
    const float* Whh1 = (const float*)d_in[6];
    const float* bih1 = (const float*)d_in[7];
    const float* bhh1 = (const float*)d_in[8];
    const float* Wlin = (const float*)d_in[9];
    const float* blin = (const float*)d_in[10];
    float* outp = (float*)d_out;

    dim3 block(256);
    dim3 grid(BATCH / 4);            // 4 waves/block, 1 batch row per wave
    hipLaunchKernelGGL(lstm2_v7, grid, block, 0, stream,
                       x, Wih0, Whh0, bih0, bhh0, Wih1, Whh1, bih1, bhh1,
                       Wlin, blin, outp);
}